// Round 1
// 139.657 us; speedup vs baseline: 1.0881x; 1.0881x over previous
//
#include <hip/hip_runtime.h>

#define SEQ 2048
#define DM 1024

typedef __attribute__((ext_vector_type(8))) short bs8;
typedef __attribute__((ext_vector_type(4))) float vf4;
typedef __attribute__((ext_vector_type(4))) unsigned int vu4;

__device__ __forceinline__ unsigned short bf16u(float f) {
  unsigned int u = __float_as_uint(f);
  u = (u + 0x7fffu + ((u >> 16) & 1u)) >> 16;
  return (unsigned short)u;
}

__device__ __forceinline__ unsigned int cvt_pk(float lo, float hi) {
  unsigned int r;
  asm("v_cvt_pk_bf16_f32 %0, %1, %2" : "=v"(r) : "v"(lo), "v"(hi));
  return r;
}

__device__ __forceinline__ float fexp2(float x) {
  float r;
  asm("v_exp_f32 %0, %1" : "=v"(r) : "v"(x));
  return r;
}

__device__ __forceinline__ void gload16(const unsigned short* g, unsigned short* l) {
  __builtin_amdgcn_global_load_lds(
      (const __attribute__((address_space(1))) unsigned int*)g,
      (__attribute__((address_space(3))) unsigned int*)l, 16, 0, 0);
}

// ---- combine: Cqk[256][1024]; rows 0..127 = Cq (h*8+r), 128..255 = Ck ----
__global__ void k_combine(const float* __restrict__ Wq, const float* __restrict__ Wk,
                          const float* __restrict__ Bm, float* __restrict__ Cqk) {
  int e = blockIdx.x * 256 + threadIdx.x;
  int which = e >> 17;
  int rem = e & 131071;
  int hr = rem >> 10;
  int j = rem & 1023;
  int h = hr >> 3, r = hr & 7;
  const float* W = which ? Wk : Wq;
  float acc = 0.f;
  #pragma unroll 8
  for (int d = 0; d < 64; d++) {
    int gd = h * 64 + d;
    acc += Bm[gd * 8 + r] * W[gd * 1024 + j];
  }
  Cqk[(size_t)(which * 128 + hr) * 1024 + j] = acc;
}

// ---- f32 -> bf16 ----
__global__ void k_cvt(const float* __restrict__ in, unsigned short* __restrict__ out, int n4) {
  int i = blockIdx.x * 256 + threadIdx.x;
  if (i >= n4) return;
  float4 v = ((const float4*)in)[i];
  ushort4 o;
  o.x = bf16u(v.x); o.y = bf16u(v.y); o.z = bf16u(v.z); o.w = bf16u(v.w);
  ((ushort4*)out)[i] = o;
}

// ---- fp32 GEMM (split-K=2): Cz[M][N] = A[M][Khalf] * W[N][Khalf]^T ----
// 256 thr, BM=64 BN=64 BK=32, 4x4/thread; z picks K-half and output buffer.
__global__ __launch_bounds__(256) void k_gemm_f32(const float* __restrict__ A,
    const float* __restrict__ W, float* __restrict__ C0, float* __restrict__ C1,
    int M, int N, int K) {
  __shared__ float As[32][68];
  __shared__ float Ws[32][68];
  int t = threadIdx.x;
  int m0 = blockIdx.x * 64, n0 = blockIdx.y * 64;
  int kz = blockIdx.z;
  float* C = kz ? C1 : C0;
  int tm = t >> 4, tn = t & 15;
  float acc[4][4];
  #pragma unroll
  for (int a = 0; a < 4; a++)
    #pragma unroll
    for (int b = 0; b < 4; b++) acc[a][b] = 0.f;

  for (int k0 = kz * 512; k0 < kz * 512 + 512; k0 += 32) {
    __syncthreads();
    #pragma unroll
    for (int i = 0; i < 2; i++) {
      int idx = t + 256 * i;
      int row = idx >> 3, c4 = idx & 7;
      float4 av = *(const float4*)&A[(size_t)(m0 + row) * K + k0 + c4 * 4];
      As[c4*4+0][row] = av.x; As[c4*4+1][row] = av.y;
      As[c4*4+2][row] = av.z; As[c4*4+3][row] = av.w;
      float4 wv = *(const float4*)&W[(size_t)(n0 + row) * K + k0 + c4 * 4];
      Ws[c4*4+0][row] = wv.x; Ws[c4*4+1][row] = wv.y;
      Ws[c4*4+2][row] = wv.z; Ws[c4*4+3][row] = wv.w;
    }
    __syncthreads();
    #pragma unroll
    for (int k = 0; k < 32; k++) {
      float4 a = *(const float4*)&As[k][tm * 4];
      float4 w = *(const float4*)&Ws[k][tn * 4];
      float av[4] = {a.x, a.y, a.z, a.w};
      float wv[4] = {w.x, w.y, w.z, w.w};
      #pragma unroll
      for (int rm = 0; rm < 4; rm++)
        #pragma unroll
        for (int cn = 0; cn < 4; cn++)
          acc[rm][cn] += av[rm] * wv[cn];
    }
  }
  #pragma unroll
  for (int rm = 0; rm < 4; rm++) {
    float4 o = {acc[rm][0], acc[rm][1], acc[rm][2], acc[rm][3]};
    *(float4*)&C[(size_t)(m0 + tm * 4 + rm) * N + n0 + tn * 4] = o;
  }
}

// ---- hi/lo split of (QKrA+QKrB) -> Qhl, Khl (bf16), Q pre-scaled ----
__global__ void k_hilo(const float* __restrict__ QA, const float* __restrict__ QB,
                       unsigned short* __restrict__ Qhl, unsigned short* __restrict__ Khl) {
  int i = blockIdx.x * 256 + threadIdx.x;      // 0..131071
  int side = i >> 16;
  int nh = i & 65535;
  int n = nh & 4095;
  int h = nh >> 12;
  size_t off = (size_t)n * 256 + side * 128 + h * 8;
  const float sc = side ? 1.0f : (1.4426950408889634f * 0.35355339059327373f);
  unsigned short* dst = (side ? Khl : Qhl) + ((size_t)h * 4096 + n) * 16;
  float4 a0 = *(const float4*)&QA[off];
  float4 a1 = *(const float4*)&QA[off + 4];
  float4 b0 = *(const float4*)&QB[off];
  float4 b1 = *(const float4*)&QB[off + 4];
  float f[8] = {a0.x+b0.x, a0.y+b0.y, a0.z+b0.z, a0.w+b0.w,
                a1.x+b1.x, a1.y+b1.y, a1.z+b1.z, a1.w+b1.w};
  unsigned short hs[8], ls[8];
  #pragma unroll
  for (int j = 0; j < 8; j++) {
    float fs = f[j] * sc;
    unsigned short h16 = bf16u(fs);
    float hf = __uint_as_float(((unsigned int)h16) << 16);
    hs[j] = h16;
    ls[j] = bf16u(fs - hf);
  }
  uint4 hv = {(unsigned int)hs[0] | ((unsigned int)hs[1] << 16),
              (unsigned int)hs[2] | ((unsigned int)hs[3] << 16),
              (unsigned int)hs[4] | ((unsigned int)hs[5] << 16),
              (unsigned int)hs[6] | ((unsigned int)hs[7] << 16)};
  uint4 lv = {(unsigned int)ls[0] | ((unsigned int)ls[1] << 16),
              (unsigned int)ls[2] | ((unsigned int)ls[3] << 16),
              (unsigned int)ls[4] | ((unsigned int)ls[5] << 16),
              (unsigned int)ls[6] | ((unsigned int)ls[7] << 16)};
  *(uint4*)dst = hv;
  *(uint4*)(dst + 8) = lv;
}

// ---- bf16 MFMA GEMM, 128x64 tile, BK=64, global_load_lds staging ----
// C = A[M][K] * W[N][K]^T. 4 waves along M (wave w: rows w*32..+31, 2x4 frags).
// LDS linear row-major [rows][64]; 16B slot s of row holds k-chunk c = s ^ key(row),
// key(row) = (row ^ (row>>3)) & 7 (pre-swizzled global source, m173 pattern).
// OUT: 0 = f32 C[M][N]; 2 = bf16 transposed C^T[N][M]
template<int OUT>
__global__ __launch_bounds__(256) void k_gemm128(const unsigned short* __restrict__ A,
    const unsigned short* __restrict__ W, void* __restrict__ Cout, int M, int N, int K) {
  __shared__ unsigned short Ah[128 * 64];     // 16 KB
  __shared__ unsigned short Bh[64 * 64];      // 8 KB
  int t = threadIdx.x, lane = t & 63, w = t >> 6;
  int gg = lane >> 4, r = lane & 15;
  int m0 = blockIdx.x * 128, n0 = blockIdx.y * 64;
  vf4 acc[2][4];
  #pragma unroll
  for (int i = 0; i < 2; i++)
    #pragma unroll
    for (int j = 0; j < 4; j++) acc[i][j] = (vf4){0.f, 0.f, 0.f, 0.f};

  // staging source pointers (k0 added per step)
  int prow = lane >> 3, pslot = lane & 7;     // 8 rows per pass, 8 slots per row
  const unsigned short* asrc[4];
  unsigned short* aldst[4];
  #pragma unroll
  for (int p = 0; p < 4; p++) {
    int rr = w * 32 + p * 8 + prow;
    int c = pslot ^ ((rr ^ (rr >> 3)) & 7);
    asrc[p] = &A[(size_t)(m0 + rr) * K + c * 8];
    aldst[p] = &Ah[(w * 32 + p * 8) * 64];
  }
  const unsigned short* bsrc[2];
  unsigned short* bldst[2];
  #pragma unroll
  for (int p = 0; p < 2; p++) {
    int rn = w * 16 + p * 8 + prow;
    int c = pslot ^ ((rn ^ (rn >> 3)) & 7);
    bsrc[p] = &W[(size_t)(n0 + rn) * K + c * 8];
    bldst[p] = &Bh[(w * 16 + p * 8) * 64];
  }

  // fragment read offsets (constant per lane)
  int aoff[2][2], boff[4][2];
  #pragma unroll
  for (int fm = 0; fm < 2; fm++) {
    int arow = w * 32 + fm * 16 + r;
    int key = (arow ^ (arow >> 3)) & 7;
    #pragma unroll
    for (int kk = 0; kk < 2; kk++)
      aoff[fm][kk] = arow * 64 + ((kk * 4 + gg) ^ key) * 8;
  }
  #pragma unroll
  for (int fn = 0; fn < 4; fn++) {
    int brow = fn * 16 + r;
    int key = (brow ^ (brow >> 3)) & 7;
    #pragma unroll
    for (int kk = 0; kk < 2; kk++)
      boff[fn][kk] = brow * 64 + ((kk * 4 + gg) ^ key) * 8;
  }

  for (int k0 = 0; k0 < K; k0 += 64) {
    __syncthreads();
    #pragma unroll
    for (int p = 0; p < 4; p++) gload16(asrc[p] + k0, aldst[p]);
    #pragma unroll
    for (int p = 0; p < 2; p++) gload16(bsrc[p] + k0, bldst[p]);
    __syncthreads();
    bs8 af[2][2], bf[4][2];
    #pragma unroll
    for (int fm = 0; fm < 2; fm++)
      #pragma unroll
      for (int kk = 0; kk < 2; kk++) af[fm][kk] = *(const bs8*)&Ah[aoff[fm][kk]];
    #pragma unroll
    for (int fn = 0; fn < 4; fn++)
      #pragma unroll
      for (int kk = 0; kk < 2; kk++) bf[fn][kk] = *(const bs8*)&Bh[boff[fn][kk]];
    #pragma unroll
    for (int kk = 0; kk < 2; kk++)
      #pragma unroll
      for (int fm = 0; fm < 2; fm++)
        #pragma unroll
        for (int fn = 0; fn < 4; fn++)
          acc[fm][fn] = __builtin_amdgcn_mfma_f32_16x16x32_bf16(af[fm][kk], bf[fn][kk], acc[fm][fn], 0, 0, 0);
  }

  #pragma unroll
  for (int fm = 0; fm < 2; fm++)
    #pragma unroll
    for (int fn = 0; fn < 4; fn++) {
      if (OUT == 2) {
        int n = n0 + fn * 16 + r;
        int m = m0 + w * 32 + fm * 16 + gg * 4;
        ushort4 st = {bf16u(acc[fm][fn][0]), bf16u(acc[fm][fn][1]),
                      bf16u(acc[fm][fn][2]), bf16u(acc[fm][fn][3])};
        *(ushort4*)&((unsigned short*)Cout)[(size_t)n * M + m] = st;
      } else {
        #pragma unroll
        for (int j = 0; j < 4; j++) {
          int m = m0 + w * 32 + fm * 16 + gg * 4 + j;
          int n = n0 + fn * 16 + r;
          ((float*)Cout)[(size_t)m * N + n] = acc[fm][fn][j];
        }
      }
    }
}

// ---- fused low-rank flash attention, MFMA scores via split-bf16 hi/lo ----
// v2: double-buffered VT (1 barrier/chunk), V+K prefetch at iteration top,
// row-sum on the MFMA pipe (ones-B accumulator), setprio around MFMA clusters.
__global__ __launch_bounds__(256, 4) void k_attn(const unsigned short* __restrict__ Qhl,
    const unsigned short* __restrict__ Khl, const unsigned short* __restrict__ Vt,
    unsigned short* __restrict__ AO) {
  int bx = blockIdx.x;
  int qt = bx & 31, h = (bx >> 5) & 15, b = bx >> 9;
  int t = threadIdx.x, lane = t & 63, w = t >> 6;
  int gg = lane >> 4, r = lane & 15;

  __shared__ unsigned short VT[2][4096];       // 16 KB double-buffered

  int qglob = b * 2048 + qt * 64 + w * 16 + r;
  bs8 bq = {0, 0, 0, 0, 0, 0, 0, 0};
  if (gg != 3)
    bq = *(const bs8*)&Qhl[((size_t)h * 4096 + qglob) * 16 + (gg == 2 ? 8 : 0)];

  // K fragment pointers (constant per lane, advanced by chunk).
  // gg==3 lanes load real (hi) data but bq==0 there, so the QK product's
  // k-subchunk 3 contribution is exactly 0 — no divergent branch needed.
  const unsigned short* Khead = &Khl[((size_t)h * 4096 + (size_t)b * 2048) * 16];
  int koff = (gg == 1) ? 8 : 0;
  const unsigned short* kp[4];
  #pragma unroll
  for (int kt = 0; kt < 4; kt++) {
    int ks = (kt & 1) * 32 + (r >> 2) * 8 + (kt >> 1) * 4 + (r & 3);
    kp[kt] = Khead + (size_t)ks * 16 + koff;
  }

  // V staging (row copy from Vt, swizzled slots)
  int vrow = t >> 2, vcl = t & 3;
  const unsigned short* vsrc = &Vt[(size_t)(h * 64 + vrow) * 4096 + (size_t)b * 2048 + vcl * 16];
  int vkey = (vrow ^ (vrow >> 2)) & 7;
  int sw0 = ((vcl * 2) ^ vkey) * 8;
  int sw1 = ((vcl * 2 + 1) ^ vkey) * 8;

  // PV read offsets (constant per lane)
  int pvoff[2][4];
  #pragma unroll
  for (int sl = 0; sl < 2; sl++)
    #pragma unroll
    for (int fn = 0; fn < 4; fn++) {
      int row = 4 * r + fn;
      int key = (row ^ (row >> 2)) & 7;
      pvoff[sl][fn] = row * 64 + ((sl * 4 + gg) ^ key) * 8;
    }

  float mrun = -INFINITY;
  vf4 acc[4];
  #pragma unroll
  for (int i = 0; i < 4; i++) acc[i] = (vf4){0.f, 0.f, 0.f, 0.f};
  vf4 accs = (vf4){0.f, 0.f, 0.f, 0.f};        // row-sum accumulator (l), MFMA ones-B

  const bs8 ones = (bs8){16256, 16256, 16256, 16256, 16256, 16256, 16256, 16256}; // bf16 1.0

  // ---- prologue: chunk 0 V -> VT[0], K frags -> af ----
  uint4 fv0 = *(const uint4*)(vsrc);
  uint4 fv1 = *(const uint4*)(vsrc + 8);
  bs8 af0 = *(const bs8*)(kp[0]);
  bs8 af1 = *(const bs8*)(kp[1]);
  bs8 af2 = *(const bs8*)(kp[2]);
  bs8 af3 = *(const bs8*)(kp[3]);
  {
    unsigned short* vd = &VT[0][vrow * 64];
    *(uint4*)(vd + sw0) = fv0;
    *(uint4*)(vd + sw1) = fv1;
  }
  __syncthreads();

  #pragma unroll 2
  for (int kc = 0; kc < 32; kc++) {
    // prefetch next chunk (clamped on last iter; consumed after full compute span)
    int nc = kc < 31 ? kc + 1 : 31;
    uint4 nv0 = *(const uint4*)(vsrc + nc * 64);
    uint4 nv1 = *(const uint4*)(vsrc + nc * 64 + 8);
    size_t nb16 = (size_t)nc * 64 * 16;
    bs8 naf0 = *(const bs8*)(kp[0] + nb16);
    bs8 naf1 = *(const bs8*)(kp[1] + nb16);
    bs8 naf2 = *(const bs8*)(kp[2] + nb16);
    bs8 naf3 = *(const bs8*)(kp[3] + nb16);

    vf4 z = (vf4){0.f, 0.f, 0.f, 0.f};
    __builtin_amdgcn_s_setprio(1);
    vf4 s0 = __builtin_amdgcn_mfma_f32_16x16x32_bf16(af0, bq, z, 0, 0, 0);
    vf4 s1 = __builtin_amdgcn_mfma_f32_16x16x32_bf16(af1, bq, z, 0, 0, 0);
    vf4 s2 = __builtin_amdgcn_mfma_f32_16x16x32_bf16(af2, bq, z, 0, 0, 0);
    vf4 s3 = __builtin_amdgcn_mfma_f32_16x16x32_bf16(af3, bq, z, 0, 0, 0);
    __builtin_amdgcn_s_setprio(0);

    float p[16];
    #pragma unroll
    for (int j = 0; j < 4; j++) {
      p[0 + j] = s0[j]; p[4 + j] = s1[j]; p[8 + j] = s2[j]; p[12 + j] = s3[j];
    }
    // max3-friendly tree
    float cm0 = fmaxf(fmaxf(p[0],  p[1]),  p[2]);
    float cm1 = fmaxf(fmaxf(p[3],  p[4]),  p[5]);
    float cm2 = fmaxf(fmaxf(p[6],  p[7]),  p[8]);
    float cm3 = fmaxf(fmaxf(p[9],  p[10]), p[11]);
    float cm4 = fmaxf(fmaxf(p[12], p[13]), p[14]);
    float cmax = fmaxf(fmaxf(fmaxf(cm0, cm1), cm2),
                       fmaxf(fmaxf(cm3, cm4), p[15]));
    cmax = fmaxf(cmax, __shfl_xor(cmax, 16));
    cmax = fmaxf(cmax, __shfl_xor(cmax, 32));

    // defer-max (T13): rescale only when max grew by > 8 (log2 units)
    if (!__all(cmax <= mrun + 8.f)) {
      float mnew = fmaxf(mrun, cmax);
      float alpha = fexp2(mrun - mnew);
      float al[4];
      #pragma unroll
      for (int j = 0; j < 4; j++) al[j] = __shfl(alpha, gg * 4 + j);
      #pragma unroll
      for (int fn = 0; fn < 4; fn++) {
        acc[fn][0] *= al[0]; acc[fn][1] *= al[1];
        acc[fn][2] *= al[2]; acc[fn][3] *= al[3];
      }
      accs[0] *= al[0]; accs[1] *= al[1];
      accs[2] *= al[2]; accs[3] *= al[3];
      mrun = mnew;
    }

    #pragma unroll
    for (int i = 0; i < 16; i++) p[i] = fexp2(p[i] - mrun);

    // pack p -> PV A-fragments
    vu4 a0 = {cvt_pk(p[0],  p[1]),  cvt_pk(p[2],  p[3]),
              cvt_pk(p[8],  p[9]),  cvt_pk(p[10], p[11])};
    vu4 a1 = {cvt_pk(p[4],  p[5]),  cvt_pk(p[6],  p[7]),
              cvt_pk(p[12], p[13]), cvt_pk(p[14], p[15])};
    bs8 apv0 = __builtin_bit_cast(bs8, a0);
    bs8 apv1 = __builtin_bit_cast(bs8, a1);

    const unsigned short* vb = &VT[kc & 1][0];
    __builtin_amdgcn_s_setprio(1);
    #pragma unroll
    for (int sl = 0; sl < 2; sl++) {
      bs8 a = sl ? apv1 : apv0;
      #pragma unroll
      for (int fn = 0; fn < 4; fn++) {
        bs8 bv = *(const bs8*)&vb[pvoff[sl][fn]];
        acc[fn] = __builtin_amdgcn_mfma_f32_16x16x32_bf16(a, bv, acc[fn], 0, 0, 0);
      }
    }
    // row-sum of P on the matrix pipe: accs[j] = l for query gg*4+j
    accs = __builtin_amdgcn_mfma_f32_16x16x32_bf16(apv0, ones, accs, 0, 0, 0);
    accs = __builtin_amdgcn_mfma_f32_16x16x32_bf16(apv1, ones, accs, 0, 0, 0);
    __builtin_amdgcn_s_setprio(0);

    af0 = naf0; af1 = naf1; af2 = naf2; af3 = naf3;

    // write NEXT chunk's V into the other buffer; single barrier per chunk.
    if (kc < 31) {
      unsigned short* vd = &VT[(kc + 1) & 1][vrow * 64];
      *(uint4*)(vd + sw0) = nv0;
      *(uint4*)(vd + sw1) = nv1;
      __syncthreads();
    }
  }

  float li[4];
  #pragma unroll
  for (int j = 0; j < 4; j++) li[j] = 1.f / accs[j];
  #pragma unroll
  for (int j = 0; j < 4; j++) {
    uint2 o;
    o.x = cvt_pk(acc[0][j] * li[j], acc[1][j] * li[j]);
    o.y = cvt_pk(acc[2][j] * li[j], acc[3][j] * li[j]);
    int qq = qt * 64 + w * 16 + gg * 4 + j;
    *(uint2*)&AO[((size_t)b * SEQ + qq) * 1024 + h * 64 + 4 * r] = o;
  }
}

extern "C" void kernel_launch(void* const* d_in, const int* in_sizes, int n_in,
                              void* d_out, int out_size, void* d_ws, size_t ws_size,
                              hipStream_t stream) {
  const float* x  = (const float*)d_in[0];
  const float* Wq = (const float*)d_in[1];
  const float* Wk = (const float*)d_in[2];
  const float* Wv = (const float*)d_in[3];
  const float* Wo = (const float*)d_in[4];
  const float* Bm = (const float*)d_in[5];
  float* out = (float*)d_out;

  char* ws = (char*)d_ws;
  float* Cqk  = (float*)ws;                    ws += (size_t)256 * 1024 * 4;     // 1 MB
  float* QKrA = (float*)ws;                    ws += (size_t)4096 * 256 * 4;     // 4 MB
  float* QKrB = (float*)ws;                    ws += (size_t)4096 * 256 * 4;     // 4 MB
  unsigned short* xh  = (unsigned short*)ws;   ws += (size_t)4096 * 1024 * 2;    // 8 MB
  unsigned short* Wvh = (unsigned short*)ws;   ws += (size_t)1024 * 1024 * 2;    // 2 MB
  unsigned short* Woh = (unsigned short*)ws;   ws += (size_t)1024 * 1024 * 2;    // 2 MB
  unsigned short* Vt  = (unsigned short*)ws;   ws += (size_t)4096 * 1024 * 2;    // 8 MB
  unsigned short* AO  = (unsigned short*)ws;   ws += (size_t)4096 * 1024 * 2;    // 8 MB
  unsigned short* Qhl = (unsigned short*)ws;   ws += (size_t)16 * 4096 * 16 * 2; // 2 MB
  unsigned short* Khl = (unsigned short*)ws;   ws += (size_t)16 * 4096 * 16 * 2; // 2 MB

  k_combine<<<1024, 256, 0, stream>>>(Wq, Wk, Bm, Cqk);
  k_cvt<<<4096, 256, 0, stream>>>(x,  xh,  1048576);
  k_cvt<<<1024, 256, 0, stream>>>(Wv, Wvh, 262144);
  k_cvt<<<1024, 256, 0, stream>>>(Wo, Woh, 262144);
  // QKr split-K=2 partials (fp32 logits)
  k_gemm_f32<<<dim3(64, 4, 2), 256, 0, stream>>>(x, Cqk, QKrA, QKrB, 4096, 256, 1024);
  k_hilo<<<512, 256, 0, stream>>>(QKrA, QKrB, Qhl, Khl);
  // Vt[1024][4096] = (x @ Wv^T)^T
  k_gemm128<2><<<dim3(32, 16), 256, 0, stream>>>(xh, Wvh, (void*)Vt, 4096, 1024, 1024);
  k_attn<<<1024, 256, 0, stream>>>(Qhl, Khl, Vt, AO);
  // out = AO @ Wo^T
  k_gemm128<0><<<dim3(32, 16), 256, 0, stream>>>(AO, Woh, (void*)out, 4096, 1024, 1024);
}

// Round 2
// 118.097 us; speedup vs baseline: 1.2867x; 1.1826x over previous
//
#include <hip/hip_runtime.h>

#define SEQ 2048
#define DM 1024

typedef __attribute__((ext_vector_type(8))) short bs8;
typedef __attribute__((ext_vector_type(4))) float vf4;
typedef __attribute__((ext_vector_type(4))) unsigned int vu4;

__device__ __forceinline__ unsigned short bf16u(float f) {
  unsigned int u = __float_as_uint(f);
  u = (u + 0x7fffu + ((u >> 16) & 1u)) >> 16;
  return (unsigned short)u;
}

__device__ __forceinline__ unsigned int cvt_pk(float lo, float hi) {
  unsigned int r;
  asm("v_cvt_pk_bf16_f32 %0, %1, %2" : "=v"(r) : "v"(lo), "v"(hi));
  return r;
}

__device__ __forceinline__ float fexp2(float x) {
  float r;
  asm("v_exp_f32 %0, %1" : "=v"(r) : "v"(x));
  return r;
}

__device__ __forceinline__ void gload16(const unsigned short* g, unsigned short* l) {
  __builtin_amdgcn_global_load_lds(
      (const __attribute__((address_space(1))) unsigned int*)g,
      (__attribute__((address_space(3))) unsigned int*)l, 16, 0, 0);
}

// ---- combine: Cqk rows 0..127 = Cq (h*8+r), 128..255 = Ck; hi/lo bf16 out ----
__global__ void k_combine(const float* __restrict__ Wq, const float* __restrict__ Wk,
                          const float* __restrict__ Bm,
                          unsigned short* __restrict__ Ch, unsigned short* __restrict__ Cl) {
  int e = blockIdx.x * 256 + threadIdx.x;
  int which = e >> 17;
  int rem = e & 131071;
  int hr = rem >> 10;
  int j = rem & 1023;
  int h = hr >> 3, r = hr & 7;
  const float* W = which ? Wk : Wq;
  float acc = 0.f;
  #pragma unroll 8
  for (int d = 0; d < 64; d++) {
    int gd = h * 64 + d;
    acc += Bm[gd * 8 + r] * W[gd * 1024 + j];
  }
  size_t idx = (size_t)(which * 128 + hr) * 1024 + j;
  unsigned short h16 = bf16u(acc);
  float hf = __uint_as_float(((unsigned int)h16) << 16);
  Ch[idx] = h16;
  Cl[idx] = bf16u(acc - hf);
}

// ---- f32 -> bf16 ----
__global__ void k_cvt(const float* __restrict__ in, unsigned short* __restrict__ out, int n4) {
  int i = blockIdx.x * 256 + threadIdx.x;
  if (i >= n4) return;
  float4 v = ((const float4*)in)[i];
  ushort4 o;
  o.x = bf16u(v.x); o.y = bf16u(v.y); o.z = bf16u(v.z); o.w = bf16u(v.w);
  ((ushort4*)out)[i] = o;
}

// ---- f32 -> bf16 hi + lo residual ----
__global__ void k_cvt_hl(const float* __restrict__ in, unsigned short* __restrict__ oh,
                         unsigned short* __restrict__ ol, int n4) {
  int i = blockIdx.x * 256 + threadIdx.x;
  if (i >= n4) return;
  float4 v = ((const float4*)in)[i];
  float f[4] = {v.x, v.y, v.z, v.w};
  ushort4 hv, lv;
  unsigned short hs[4], ls[4];
  #pragma unroll
  for (int j = 0; j < 4; j++) {
    unsigned short h16 = bf16u(f[j]);
    float hf = __uint_as_float(((unsigned int)h16) << 16);
    hs[j] = h16;
    ls[j] = bf16u(f[j] - hf);
  }
  hv.x = hs[0]; hv.y = hs[1]; hv.z = hs[2]; hv.w = hs[3];
  lv.x = ls[0]; lv.y = ls[1]; lv.z = ls[2]; lv.w = ls[3];
  ((ushort4*)oh)[i] = hv;
  ((ushort4*)ol)[i] = lv;
}

// ---- QKr via MFMA hi/lo (3-term): C = x @ Cqk^T, f32 partials, split-K=2 ----
// M=4096, N=256, K=1024. 64x64 tile, BK=64, 4 waves along M (16 rows each).
// LDS pre-swizzled (m173): slot s of row holds k-chunk c = s ^ key(row),
// key(row) = (row ^ (row>>3)) & 7.
__global__ __launch_bounds__(256) void k_qkr(
    const unsigned short* __restrict__ Xh, const unsigned short* __restrict__ Xl,
    const unsigned short* __restrict__ Bh_, const unsigned short* __restrict__ Bl_,
    float* __restrict__ C0, float* __restrict__ C1) {
  const int K = 1024, N = 256;
  __shared__ unsigned short Sah[64 * 64];   // 8 KB each
  __shared__ unsigned short Sal[64 * 64];
  __shared__ unsigned short Sbh[64 * 64];
  __shared__ unsigned short Sbl[64 * 64];
  int t = threadIdx.x, lane = t & 63, w = t >> 6;
  int gg = lane >> 4, r = lane & 15;
  int m0 = blockIdx.x * 64, n0 = blockIdx.y * 64;
  int kz = blockIdx.z;
  float* C = kz ? C1 : C0;
  vf4 acc[4];
  #pragma unroll
  for (int fn = 0; fn < 4; fn++) acc[fn] = (vf4){0.f, 0.f, 0.f, 0.f};

  int prow = lane >> 3, pslot = lane & 7;
  const unsigned short *ah_src[2], *al_src[2], *bh_src[2], *bl_src[2];
  unsigned short *ah_dst[2], *al_dst[2], *bh_dst[2], *bl_dst[2];
  #pragma unroll
  for (int p = 0; p < 2; p++) {
    int rr = w * 16 + p * 8 + prow;
    int c = pslot ^ ((rr ^ (rr >> 3)) & 7);
    size_t ga = (size_t)(m0 + rr) * K + (size_t)kz * 512 + c * 8;
    ah_src[p] = Xh + ga;  al_src[p] = Xl + ga;
    size_t gb = (size_t)(n0 + rr) * K + (size_t)kz * 512 + c * 8;
    bh_src[p] = Bh_ + gb; bl_src[p] = Bl_ + gb;
    int ldo = (w * 16 + p * 8) * 64;
    ah_dst[p] = &Sah[ldo]; al_dst[p] = &Sal[ldo];
    bh_dst[p] = &Sbh[ldo]; bl_dst[p] = &Sbl[ldo];
  }

  int aoff[2], boff[4][2];
  {
    int arow = w * 16 + r;
    int key = (arow ^ (arow >> 3)) & 7;
    #pragma unroll
    for (int kk = 0; kk < 2; kk++) aoff[kk] = arow * 64 + ((kk * 4 + gg) ^ key) * 8;
  }
  #pragma unroll
  for (int fn = 0; fn < 4; fn++) {
    int brow = fn * 16 + r;
    int key = (brow ^ (brow >> 3)) & 7;
    #pragma unroll
    for (int kk = 0; kk < 2; kk++) boff[fn][kk] = brow * 64 + ((kk * 4 + gg) ^ key) * 8;
  }

  for (int k0 = 0; k0 < 512; k0 += 64) {
    __syncthreads();
    #pragma unroll
    for (int p = 0; p < 2; p++) {
      gload16(ah_src[p] + k0, ah_dst[p]);
      gload16(al_src[p] + k0, al_dst[p]);
      gload16(bh_src[p] + k0, bh_dst[p]);
      gload16(bl_src[p] + k0, bl_dst[p]);
    }
    __syncthreads();
    bs8 afh[2], afl[2], bfh[4][2], bfl[4][2];
    #pragma unroll
    for (int kk = 0; kk < 2; kk++) {
      afh[kk] = *(const bs8*)&Sah[aoff[kk]];
      afl[kk] = *(const bs8*)&Sal[aoff[kk]];
    }
    #pragma unroll
    for (int fn = 0; fn < 4; fn++)
      #pragma unroll
      for (int kk = 0; kk < 2; kk++) {
        bfh[fn][kk] = *(const bs8*)&Sbh[boff[fn][kk]];
        bfl[fn][kk] = *(const bs8*)&Sbl[boff[fn][kk]];
      }
    #pragma unroll
    for (int kk = 0; kk < 2; kk++)
      #pragma unroll
      for (int fn = 0; fn < 4; fn++) {
        acc[fn] = __builtin_amdgcn_mfma_f32_16x16x32_bf16(afh[kk], bfh[fn][kk], acc[fn], 0, 0, 0);
        acc[fn] = __builtin_amdgcn_mfma_f32_16x16x32_bf16(afh[kk], bfl[fn][kk], acc[fn], 0, 0, 0);
        acc[fn] = __builtin_amdgcn_mfma_f32_16x16x32_bf16(afl[kk], bfh[fn][kk], acc[fn], 0, 0, 0);
      }
  }

  #pragma unroll
  for (int fn = 0; fn < 4; fn++)
    #pragma unroll
    for (int j = 0; j < 4; j++) {
      int m = m0 + w * 16 + gg * 4 + j;
      int n = n0 + fn * 16 + r;
      C[(size_t)m * N + n] = acc[fn][j];
    }
}

// ---- hi/lo split of (QKrA+QKrB) -> Qhl, Khl (bf16), Q pre-scaled ----
__global__ void k_hilo(const float* __restrict__ QA, const float* __restrict__ QB,
                       unsigned short* __restrict__ Qhl, unsigned short* __restrict__ Khl) {
  int i = blockIdx.x * 256 + threadIdx.x;      // 0..131071
  int side = i >> 16;
  int nh = i & 65535;
  int n = nh & 4095;
  int h = nh >> 12;
  size_t off = (size_t)n * 256 + side * 128 + h * 8;
  const float sc = side ? 1.0f : (1.4426950408889634f * 0.35355339059327373f);
  unsigned short* dst = (side ? Khl : Qhl) + ((size_t)h * 4096 + n) * 16;
  float4 a0 = *(const float4*)&QA[off];
  float4 a1 = *(const float4*)&QA[off + 4];
  float4 b0 = *(const float4*)&QB[off];
  float4 b1 = *(const float4*)&QB[off + 4];
  float f[8] = {a0.x+b0.x, a0.y+b0.y, a0.z+b0.z, a0.w+b0.w,
                a1.x+b1.x, a1.y+b1.y, a1.z+b1.z, a1.w+b1.w};
  unsigned short hs[8], ls[8];
  #pragma unroll
  for (int j = 0; j < 8; j++) {
    float fs = f[j] * sc;
    unsigned short h16 = bf16u(fs);
    float hf = __uint_as_float(((unsigned int)h16) << 16);
    hs[j] = h16;
    ls[j] = bf16u(fs - hf);
  }
  uint4 hv = {(unsigned int)hs[0] | ((unsigned int)hs[1] << 16),
              (unsigned int)hs[2] | ((unsigned int)hs[3] << 16),
              (unsigned int)hs[4] | ((unsigned int)hs[5] << 16),
              (unsigned int)hs[6] | ((unsigned int)hs[7] << 16)};
  uint4 lv = {(unsigned int)ls[0] | ((unsigned int)ls[1] << 16),
              (unsigned int)ls[2] | ((unsigned int)ls[3] << 16),
              (unsigned int)ls[4] | ((unsigned int)ls[5] << 16),
              (unsigned int)ls[6] | ((unsigned int)ls[7] << 16)};
  *(uint4*)dst = hv;
  *(uint4*)(dst + 8) = lv;
}

// ---- bf16 MFMA GEMM, 128x64 tile, BK=64, global_load_lds staging ----
// C = A[M][K] * W[N][K]^T. 4 waves along M (wave w: rows w*32..+31, 2x4 frags).
// OUT: 0 = f32 C[M][N]; 2 = bf16 transposed C^T[N][M]
template<int OUT>
__global__ __launch_bounds__(256) void k_gemm128(const unsigned short* __restrict__ A,
    const unsigned short* __restrict__ W, void* __restrict__ Cout, int M, int N, int K) {
  __shared__ unsigned short Ah[128 * 64];     // 16 KB
  __shared__ unsigned short Bh[64 * 64];      // 8 KB
  int t = threadIdx.x, lane = t & 63, w = t >> 6;
  int gg = lane >> 4, r = lane & 15;
  int m0 = blockIdx.x * 128, n0 = blockIdx.y * 64;
  vf4 acc[2][4];
  #pragma unroll
  for (int i = 0; i < 2; i++)
    #pragma unroll
    for (int j = 0; j < 4; j++) acc[i][j] = (vf4){0.f, 0.f, 0.f, 0.f};

  int prow = lane >> 3, pslot = lane & 7;
  const unsigned short* asrc[4];
  unsigned short* aldst[4];
  #pragma unroll
  for (int p = 0; p < 4; p++) {
    int rr = w * 32 + p * 8 + prow;
    int c = pslot ^ ((rr ^ (rr >> 3)) & 7);
    asrc[p] = &A[(size_t)(m0 + rr) * K + c * 8];
    aldst[p] = &Ah[(w * 32 + p * 8) * 64];
  }
  const unsigned short* bsrc[2];
  unsigned short* bldst[2];
  #pragma unroll
  for (int p = 0; p < 2; p++) {
    int rn = w * 16 + p * 8 + prow;
    int c = pslot ^ ((rn ^ (rn >> 3)) & 7);
    bsrc[p] = &W[(size_t)(n0 + rn) * K + c * 8];
    bldst[p] = &Bh[(w * 16 + p * 8) * 64];
  }

  int aoff[2][2], boff[4][2];
  #pragma unroll
  for (int fm = 0; fm < 2; fm++) {
    int arow = w * 32 + fm * 16 + r;
    int key = (arow ^ (arow >> 3)) & 7;
    #pragma unroll
    for (int kk = 0; kk < 2; kk++)
      aoff[fm][kk] = arow * 64 + ((kk * 4 + gg) ^ key) * 8;
  }
  #pragma unroll
  for (int fn = 0; fn < 4; fn++) {
    int brow = fn * 16 + r;
    int key = (brow ^ (brow >> 3)) & 7;
    #pragma unroll
    for (int kk = 0; kk < 2; kk++)
      boff[fn][kk] = brow * 64 + ((kk * 4 + gg) ^ key) * 8;
  }

  for (int k0 = 0; k0 < K; k0 += 64) {
    __syncthreads();
    #pragma unroll
    for (int p = 0; p < 4; p++) gload16(asrc[p] + k0, aldst[p]);
    #pragma unroll
    for (int p = 0; p < 2; p++) gload16(bsrc[p] + k0, bldst[p]);
    __syncthreads();
    bs8 af[2][2], bf[4][2];
    #pragma unroll
    for (int fm = 0; fm < 2; fm++)
      #pragma unroll
      for (int kk = 0; kk < 2; kk++) af[fm][kk] = *(const bs8*)&Ah[aoff[fm][kk]];
    #pragma unroll
    for (int fn = 0; fn < 4; fn++)
      #pragma unroll
      for (int kk = 0; kk < 2; kk++) bf[fn][kk] = *(const bs8*)&Bh[boff[fn][kk]];
    #pragma unroll
    for (int kk = 0; kk < 2; kk++)
      #pragma unroll
      for (int fm = 0; fm < 2; fm++)
        #pragma unroll
        for (int fn = 0; fn < 4; fn++)
          acc[fm][fn] = __builtin_amdgcn_mfma_f32_16x16x32_bf16(af[fm][kk], bf[fn][kk], acc[fm][fn], 0, 0, 0);
  }

  #pragma unroll
  for (int fm = 0; fm < 2; fm++)
    #pragma unroll
    for (int fn = 0; fn < 4; fn++) {
      if (OUT == 2) {
        int n = n0 + fn * 16 + r;
        int m = m0 + w * 32 + fm * 16 + gg * 4;
        ushort4 st = {bf16u(acc[fm][fn][0]), bf16u(acc[fm][fn][1]),
                      bf16u(acc[fm][fn][2]), bf16u(acc[fm][fn][3])};
        *(ushort4*)&((unsigned short*)Cout)[(size_t)n * M + m] = st;
      } else {
        #pragma unroll
        for (int j = 0; j < 4; j++) {
          int m = m0 + w * 32 + fm * 16 + gg * 4 + j;
          int n = n0 + fn * 16 + r;
          ((float*)Cout)[(size_t)m * N + n] = acc[fm][fn][j];
        }
      }
    }
}

// ---- fused low-rank flash attention, MFMA scores via split-bf16 hi/lo ----
// v2: double-buffered VT (1 barrier/chunk), V+K prefetch at iteration top,
// row-sum on the MFMA pipe (ones-B accumulator), setprio around MFMA clusters.
__global__ __launch_bounds__(256, 4) void k_attn(const unsigned short* __restrict__ Qhl,
    const unsigned short* __restrict__ Khl, const unsigned short* __restrict__ Vt,
    unsigned short* __restrict__ AO) {
  int bx = blockIdx.x;
  int qt = bx & 31, h = (bx >> 5) & 15, b = bx >> 9;
  int t = threadIdx.x, lane = t & 63, w = t >> 6;
  int gg = lane >> 4, r = lane & 15;

  __shared__ unsigned short VT[2][4096];       // 16 KB double-buffered

  int qglob = b * 2048 + qt * 64 + w * 16 + r;
  bs8 bq = {0, 0, 0, 0, 0, 0, 0, 0};
  if (gg != 3)
    bq = *(const bs8*)&Qhl[((size_t)h * 4096 + qglob) * 16 + (gg == 2 ? 8 : 0)];

  const unsigned short* Khead = &Khl[((size_t)h * 4096 + (size_t)b * 2048) * 16];
  int koff = (gg == 1) ? 8 : 0;
  const unsigned short* kp[4];
  #pragma unroll
  for (int kt = 0; kt < 4; kt++) {
    int ks = (kt & 1) * 32 + (r >> 2) * 8 + (kt >> 1) * 4 + (r & 3);
    kp[kt] = Khead + (size_t)ks * 16 + koff;
  }

  int vrow = t >> 2, vcl = t & 3;
  const unsigned short* vsrc = &Vt[(size_t)(h * 64 + vrow) * 4096 + (size_t)b * 2048 + vcl * 16];
  int vkey = (vrow ^ (vrow >> 2)) & 7;
  int sw0 = ((vcl * 2) ^ vkey) * 8;
  int sw1 = ((vcl * 2 + 1) ^ vkey) * 8;

  int pvoff[2][4];
  #pragma unroll
  for (int sl = 0; sl < 2; sl++)
    #pragma unroll
    for (int fn = 0; fn < 4; fn++) {
      int row = 4 * r + fn;
      int key = (row ^ (row >> 2)) & 7;
      pvoff[sl][fn] = row * 64 + ((sl * 4 + gg) ^ key) * 8;
    }

  float mrun = -INFINITY;
  vf4 acc[4];
  #pragma unroll
  for (int i = 0; i < 4; i++) acc[i] = (vf4){0.f, 0.f, 0.f, 0.f};
  vf4 accs = (vf4){0.f, 0.f, 0.f, 0.f};        // row-sum accumulator (l), MFMA ones-B

  const bs8 ones = (bs8){16256, 16256, 16256, 16256, 16256, 16256, 16256, 16256}; // bf16 1.0

  // ---- prologue: chunk 0 V -> VT[0], K frags -> af ----
  uint4 fv0 = *(const uint4*)(vsrc);
  uint4 fv1 = *(const uint4*)(vsrc + 8);
  bs8 af0 = *(const bs8*)(kp[0]);
  bs8 af1 = *(const bs8*)(kp[1]);
  bs8 af2 = *(const bs8*)(kp[2]);
  bs8 af3 = *(const bs8*)(kp[3]);
  {
    unsigned short* vd = &VT[0][vrow * 64];
    *(uint4*)(vd + sw0) = fv0;
    *(uint4*)(vd + sw1) = fv1;
  }
  __syncthreads();

  #pragma unroll 2
  for (int kc = 0; kc < 32; kc++) {
    int nc = kc < 31 ? kc + 1 : 31;
    uint4 nv0 = *(const uint4*)(vsrc + nc * 64);
    uint4 nv1 = *(const uint4*)(vsrc + nc * 64 + 8);
    size_t nb16 = (size_t)nc * 64 * 16;
    bs8 naf0 = *(const bs8*)(kp[0] + nb16);
    bs8 naf1 = *(const bs8*)(kp[1] + nb16);
    bs8 naf2 = *(const bs8*)(kp[2] + nb16);
    bs8 naf3 = *(const bs8*)(kp[3] + nb16);

    vf4 z = (vf4){0.f, 0.f, 0.f, 0.f};
    __builtin_amdgcn_s_setprio(1);
    vf4 s0 = __builtin_amdgcn_mfma_f32_16x16x32_bf16(af0, bq, z, 0, 0, 0);
    vf4 s1 = __builtin_amdgcn_mfma_f32_16x16x32_bf16(af1, bq, z, 0, 0, 0);
    vf4 s2 = __builtin_amdgcn_mfma_f32_16x16x32_bf16(af2, bq, z, 0, 0, 0);
    vf4 s3 = __builtin_amdgcn_mfma_f32_16x16x32_bf16(af3, bq, z, 0, 0, 0);
    __builtin_amdgcn_s_setprio(0);

    float p[16];
    #pragma unroll
    for (int j = 0; j < 4; j++) {
      p[0 + j] = s0[j]; p[4 + j] = s1[j]; p[8 + j] = s2[j]; p[12 + j] = s3[j];
    }
    float cm0 = fmaxf(fmaxf(p[0],  p[1]),  p[2]);
    float cm1 = fmaxf(fmaxf(p[3],  p[4]),  p[5]);
    float cm2 = fmaxf(fmaxf(p[6],  p[7]),  p[8]);
    float cm3 = fmaxf(fmaxf(p[9],  p[10]), p[11]);
    float cm4 = fmaxf(fmaxf(p[12], p[13]), p[14]);
    float cmax = fmaxf(fmaxf(fmaxf(cm0, cm1), cm2),
                       fmaxf(fmaxf(cm3, cm4), p[15]));
    cmax = fmaxf(cmax, __shfl_xor(cmax, 16));
    cmax = fmaxf(cmax, __shfl_xor(cmax, 32));

    if (!__all(cmax <= mrun + 8.f)) {
      float mnew = fmaxf(mrun, cmax);
      float alpha = fexp2(mrun - mnew);
      float al[4];
      #pragma unroll
      for (int j = 0; j < 4; j++) al[j] = __shfl(alpha, gg * 4 + j);
      #pragma unroll
      for (int fn = 0; fn < 4; fn++) {
        acc[fn][0] *= al[0]; acc[fn][1] *= al[1];
        acc[fn][2] *= al[2]; acc[fn][3] *= al[3];
      }
      accs[0] *= al[0]; accs[1] *= al[1];
      accs[2] *= al[2]; accs[3] *= al[3];
      mrun = mnew;
    }

    #pragma unroll
    for (int i = 0; i < 16; i++) p[i] = fexp2(p[i] - mrun);

    vu4 a0 = {cvt_pk(p[0],  p[1]),  cvt_pk(p[2],  p[3]),
              cvt_pk(p[8],  p[9]),  cvt_pk(p[10], p[11])};
    vu4 a1 = {cvt_pk(p[4],  p[5]),  cvt_pk(p[6],  p[7]),
              cvt_pk(p[12], p[13]), cvt_pk(p[14], p[15])};
    bs8 apv0 = __builtin_bit_cast(bs8, a0);
    bs8 apv1 = __builtin_bit_cast(bs8, a1);

    const unsigned short* vb = &VT[kc & 1][0];
    __builtin_amdgcn_s_setprio(1);
    #pragma unroll
    for (int sl = 0; sl < 2; sl++) {
      bs8 a = sl ? apv1 : apv0;
      #pragma unroll
      for (int fn = 0; fn < 4; fn++) {
        bs8 bv = *(const bs8*)&vb[pvoff[sl][fn]];
        acc[fn] = __builtin_amdgcn_mfma_f32_16x16x32_bf16(a, bv, acc[fn], 0, 0, 0);
      }
    }
    accs = __builtin_amdgcn_mfma_f32_16x16x32_bf16(apv0, ones, accs, 0, 0, 0);
    accs = __builtin_amdgcn_mfma_f32_16x16x32_bf16(apv1, ones, accs, 0, 0, 0);
    __builtin_amdgcn_s_setprio(0);

    af0 = naf0; af1 = naf1; af2 = naf2; af3 = naf3;

    if (kc < 31) {
      unsigned short* vd = &VT[(kc + 1) & 1][vrow * 64];
      *(uint4*)(vd + sw0) = nv0;
      *(uint4*)(vd + sw1) = nv1;
      __syncthreads();
    }
  }

  float li[4];
  #pragma unroll
  for (int j = 0; j < 4; j++) li[j] = 1.f / accs[j];
  #pragma unroll
  for (int j = 0; j < 4; j++) {
    uint2 o;
    o.x = cvt_pk(acc[0][j] * li[j], acc[1][j] * li[j]);
    o.y = cvt_pk(acc[2][j] * li[j], acc[3][j] * li[j]);
    int qq = qt * 64 + w * 16 + gg * 4 + j;
    *(uint2*)&AO[((size_t)b * SEQ + qq) * 1024 + h * 64 + 4 * r] = o;
  }
}

extern "C" void kernel_launch(void* const* d_in, const int* in_sizes, int n_in,
                              void* d_out, int out_size, void* d_ws, size_t ws_size,
                              hipStream_t stream) {
  const float* x  = (const float*)d_in[0];
  const float* Wq = (const float*)d_in[1];
  const float* Wk = (const float*)d_in[2];
  const float* Wv = (const float*)d_in[3];
  const float* Wo = (const float*)d_in[4];
  const float* Bm = (const float*)d_in[5];
  float* out = (float*)d_out;

  char* ws = (char*)d_ws;
  unsigned short* Cqkh = (unsigned short*)ws;  ws += (size_t)256 * 1024 * 2;     // 0.5 MB
  unsigned short* Cqkl = (unsigned short*)ws;  ws += (size_t)256 * 1024 * 2;     // 0.5 MB
  float* QKrA = (float*)ws;                    ws += (size_t)4096 * 256 * 4;     // 4 MB
  float* QKrB = (float*)ws;                    ws += (size_t)4096 * 256 * 4;     // 4 MB
  unsigned short* xh  = (unsigned short*)ws;   ws += (size_t)4096 * 1024 * 2;    // 8 MB
  unsigned short* Wvh = (unsigned short*)ws;   ws += (size_t)1024 * 1024 * 2;    // 2 MB
  unsigned short* Woh = (unsigned short*)ws;   ws += (size_t)1024 * 1024 * 2;    // 2 MB
  unsigned short* Vt  = (unsigned short*)ws;   ws += (size_t)4096 * 1024 * 2;    // 8 MB
  unsigned short* AO  = (unsigned short*)ws;   ws += (size_t)4096 * 1024 * 2;    // 8 MB
  unsigned short* Qhl = (unsigned short*)ws;   ws += (size_t)16 * 4096 * 16 * 2; // 2 MB
  unsigned short* Khl = (unsigned short*)ws;   ws += (size_t)16 * 4096 * 16 * 2; // 2 MB
  // xl aliases AO: xl is dead after k_qkr; AO is first written by k_attn later.
  unsigned short* xl = AO;

  k_combine<<<1024, 256, 0, stream>>>(Wq, Wk, Bm, Cqkh, Cqkl);
  k_cvt_hl<<<4096, 256, 0, stream>>>(x, xh, xl, 1048576);
  k_cvt<<<1024, 256, 0, stream>>>(Wv, Wvh, 262144);
  k_cvt<<<1024, 256, 0, stream>>>(Wo, Woh, 262144);
  // QKr split-K=2 partials (f32) on the matrix pipe, 3-term hi/lo
  k_qkr<<<dim3(64, 4, 2), 256, 0, stream>>>(xh, xl, Cqkh, Cqkl, QKrA, QKrB);
  k_hilo<<<512, 256, 0, stream>>>(QKrA, QKrB, Qhl, Khl);
  // Vt[1024][4096] = (x @ Wv^T)^T
  k_gemm128<2><<<dim3(32, 16), 256, 0, stream>>>(xh, Wvh, (void*)Vt, 4096, 1024, 1024);
  k_attn<<<1024, 256, 0, stream>>>(Qhl, Khl, Vt, AO);
  // out = AO @ Wo^T
  k_gemm128<0><<<dim3(32, 16), 256, 0, stream>>>(AO, Woh, (void*)out, 4096, 1024, 1024);
}